// Round 7
// baseline (113.525 us; speedup 1.0000x reference)
//
#include <hip/hip_runtime.h>

// ---------------- problem constants ----------------
constexpr int BS = 4, P_PER = 12000, NP = BS * P_PER;      // 48000 pillars
constexpr int XL = 432, YL = 496, NPTS = 32;
constexpr int XQ = XL / 4;                                 // 108 float4 per row
constexpr int NS = 3 * NPTS;                               // 96 (c,k) slabs
constexpr int YX = YL * XL;                                // 214272

constexpr long long SZ_P   = (long long)NP * NPTS * 3;        // 4,608,000
constexpr long long SZ_C   = (long long)NP * 3;               // 144,000
constexpr long long SZ_N   = NP;                              // 48,000
constexpr long long SZ_ALL = (long long)BS * 3 * NPTS * YL * XL; // 82,280,448
constexpr long long SZ_CTR = (long long)BS * 3 * YL * XL;     // 2,571,264

constexpr long long OFF_ALL = SZ_P + SZ_C + SZ_N;             // 4,800,000
constexpr long long OFF_CTR = OFF_ALL + SZ_ALL;               // 87,080,448

constexpr int STRIP = 2;                   // iy rows per block
constexpr int CW  = STRIP * XL;            // 864 cells per block
constexpr int CWQ = CW / 4;                // 216 float4 units per (slab, block)
constexpr int MAXJ = 60;    // staged pillars per chunk (avg 48.4 / 2 rows)
constexpr int JCAP = 127;   // col2j is int8; j >= JCAP treated as empty

// clang ext-vector float4 — accepted by __builtin_nontemporal_store
typedef float nt4 __attribute__((ext_vector_type(4)));

// mega-kernel block partition
constexpr int NB_ROW  = BS * YL / STRIP;                          // 992
constexpr int NB_CVT  = (int)((SZ_C / 4 + SZ_N / 4 + 255) / 256); // 188
constexpr int NB_COPY = (int)(SZ_P / 4 / 256);                    // 4500 exact
constexpr int NB_MEGA = NB_ROW + NB_CVT + NB_COPY;                // 5680

// ---------------- map build: cell -> pillar index ----------------
__global__ __launch_bounds__(256) void build_map(const int* __restrict__ coors,
                                                 int* __restrict__ map)
{
    int p = blockIdx.x * 256 + threadIdx.x;
    if (p >= NP) return;
    int b  = coors[3 * p + 0];
    int ix = coors[3 * p + 1];
    int iy = coors[3 * p + 2];
    map[(b * YL + iy) * XL + ix] = p;
}

// ---------------- mega kernel: row-pairs + convert + copy in one grid ----------
__global__ __launch_bounds__(256) void mega_kernel(
    const float* __restrict__ pillars, const int* __restrict__ coors,
    const int* __restrict__ npoints, const int* __restrict__ map,
    float* __restrict__ out)
{
    const int bid = blockIdx.x;
    const int t   = threadIdx.x;

    if (bid >= NB_ROW) {
        if (bid < NB_ROW + NB_CVT) {
            // outputs 1,2: coors / npoints int32 -> float32
            constexpr int NC = (int)(SZ_C / 4);   // 36000 int4 units
            constexpr int NN = (int)(SZ_N / 4);   // 12000
            int u = (bid - NB_ROW) * 256 + t;
            if (u >= NC + NN) return;
            int4 a; long long dst;
            if (u < NC) { a = reinterpret_cast<const int4*>(coors)[u]; dst = SZ_P / 4 + u; }
            else { a = reinterpret_cast<const int4*>(npoints)[u - NC]; dst = SZ_P / 4 + NC + (u - NC); }
            nt4 o = {(float)a.x, (float)a.y, (float)a.z, (float)a.w};
            __builtin_nontemporal_store(o, reinterpret_cast<nt4*>(out) + dst);
        } else {
            // output region 0: pillars passthrough, fully coalesced
            long long u = (long long)(bid - NB_ROW - NB_CVT) * 256 + t; // < 1,152,000
            nt4 v = reinterpret_cast<const nt4*>(pillars)[u];
            __builtin_nontemporal_store(v, reinterpret_cast<nt4*>(out) + u);
        }
        return;
    }

    // ---- row-pair section: one block per (b, iy0=2*r) ----
    __shared__ float data[MAXJ][97];        // 23,280 B
    __shared__ float ctr[MAXJ * 3];         //    720 B
    __shared__ signed char col2j[CW];       //    864 B
    __shared__ int jlist[JCAP + 1];         //    512 B
    __shared__ int cnt;

    const int b   = bid / (YL / STRIP);
    const int iy0 = (bid % (YL / STRIP)) * STRIP;

    if (t == 0) cnt = 0;
    __syncthreads();

    const int* mrow = map + (b * YL + iy0) * XL;   // 864 consecutive cells
    for (int x = t; x < CW; x += 256) {
        int p = mrow[x];
        if (p >= 0) {
            int j = atomicAdd(&cnt, 1);
            if (j < JCAP) { jlist[j] = p; col2j[x] = (signed char)j; }
            else col2j[x] = -1;
        } else {
            col2j[x] = -1;
        }
    }
    __syncthreads();
    const int nOcc = (cnt < JCAP) ? cnt : JCAP;
    const int nChunks = (nOcc <= MAXJ) ? 1 : (nOcc + MAXJ - 1) / MAXJ;

    float* out_all = out + OFF_ALL + (long long)b * NS * YX + (long long)iy0 * XL;
    float* out_ctr = out + OFF_CTR + (long long)b * 3 * YX + (long long)iy0 * XL;

    for (int ch = 0; ch < nChunks; ++ch) {
        const int jbase = ch * MAXJ;
        int chunkN = nOcc - jbase;
        if (chunkN > MAXJ) chunkN = MAXJ;
        if (chunkN < 0) chunkN = 0;

        // stage pillar data: 24 float4 per pillar, read once chip-wide
        for (int i = t; i < chunkN * 24; i += 256) {
            int jl = i / 24, e4 = i % 24;
            float4 v = reinterpret_cast<const float4*>(pillars)
                           [(long long)jlist[jbase + jl] * 24 + e4];
            data[jl][e4 * 4 + 0] = v.x;
            data[jl][e4 * 4 + 1] = v.y;
            data[jl][e4 * 4 + 2] = v.z;
            data[jl][e4 * 4 + 3] = v.w;
        }
        __syncthreads();

        // centers from staged data
        for (int i = t; i < chunkN * 3; i += 256) {
            int jl = i / 3, c = i % 3;
            float s = 0.f;
#pragma unroll
            for (int k = 0; k < NPTS; ++k) s += data[jl][k * 3 + c];
            ctr[i] = s / (float)npoints[jlist[jbase + jl]];
        }
        __syncthreads();

        if (ch == 0) {
            // pillar_all: 96 slabs x 216 float4 (3456 B contiguous per slab),
            // coalesced nontemporal stores, incremental (s, qq, ptr)
            {
                int s  = t / CWQ;               // 0 or 1
                int qq = t - s * CWQ;
                float* pa = out_all + (long long)s * YX + (long long)qq * 4;
                const unsigned int* cj4 = reinterpret_cast<const unsigned int*>(col2j);
                for (int i = t; i < NS * CWQ; i += 256) {
                    int e = (s & 31) * 3 + (s >> 5);   // element offset k*3+c
                    unsigned int cc = cj4[qq];         // 4 packed int8 slots
                    nt4 o;
                    int j0 = (int)(signed char)(cc & 0xff);
                    int j1 = (int)(signed char)((cc >> 8) & 0xff);
                    int j2 = (int)(signed char)((cc >> 16) & 0xff);
                    int j3 = (int)(signed char)(cc >> 24);
                    o.x = ((unsigned)j0 < MAXJ) ? data[j0][e] : 0.f;
                    o.y = ((unsigned)j1 < MAXJ) ? data[j1][e] : 0.f;
                    o.z = ((unsigned)j2 < MAXJ) ? data[j2][e] : 0.f;
                    o.w = ((unsigned)j3 < MAXJ) ? data[j3][e] : 0.f;
                    __builtin_nontemporal_store(o, reinterpret_cast<nt4*>(pa));
                    // advance 256 units = 1 slab + 40 units
                    s += 1; qq += 40;
                    long long step = (long long)YX + 160;
                    if (qq >= CWQ) { qq -= CWQ; s += 1; step = 2LL * YX - 704; }
                    pa += step;
                }
            }
            // pillar_center: 3 slabs x 216 float4
            {
                const unsigned int* cj4 = reinterpret_cast<const unsigned int*>(col2j);
                for (int i = t; i < 3 * CWQ; i += 256) {
                    int c = i / CWQ, qq = i - c * CWQ;
                    unsigned int cc = cj4[qq];
                    nt4 o;
                    int j0 = (int)(signed char)(cc & 0xff);
                    int j1 = (int)(signed char)((cc >> 8) & 0xff);
                    int j2 = (int)(signed char)((cc >> 16) & 0xff);
                    int j3 = (int)(signed char)(cc >> 24);
                    o.x = ((unsigned)j0 < MAXJ) ? ctr[j0 * 3 + c] : 0.f;
                    o.y = ((unsigned)j1 < MAXJ) ? ctr[j1 * 3 + c] : 0.f;
                    o.z = ((unsigned)j2 < MAXJ) ? ctr[j2 * 3 + c] : 0.f;
                    o.w = ((unsigned)j3 < MAXJ) ? ctr[j3 * 3 + c] : 0.f;
                    __builtin_nontemporal_store(o,
                        reinterpret_cast<nt4*>(out_ctr + (long long)c * YX + qq * 4));
                }
            }
        } else {
            // overflow chunk (~5% of blocks): scalar rewrites of occupied cols
            for (int i = t; i < CW * NS; i += 256) {
                int x = i % CW, s = i / CW;
                int j = col2j[x];
                if (j >= jbase && j < jbase + chunkN) {
                    int e = (s & 31) * 3 + (s >> 5);
                    out_all[(long long)s * YX + x] = data[j - jbase][e];
                }
            }
            for (int i = t; i < CW * 3; i += 256) {
                int x = i % CW, c = i / CW;
                int j = col2j[x];
                if (j >= jbase && j < jbase + chunkN)
                    out_ctr[(long long)c * YX + x] = ctr[(j - jbase) * 3 + c];
            }
        }
        __syncthreads();
    }
}

// ---------------- fallback path (ws too small): memset + scatter ----------------
__global__ __launch_bounds__(256) void scatter_kernel(
    const float* __restrict__ pillars, const int* __restrict__ coors,
    const int* __restrict__ npoints, float* __restrict__ out)
{
    int tid = blockIdx.x * blockDim.x + threadIdx.x;
    if (tid < NP * NPTS) {
        int p = tid / NPTS, k = tid % NPTS;
        int b = coors[3 * p], ix = coors[3 * p + 1], iy = coors[3 * p + 2];
#pragma unroll
        for (int c = 0; c < 3; ++c) {
            float val = pillars[(long long)p * 96 + k * 3 + c];
            long long e = OFF_ALL + ((((long long)(b * 3 + c) * NPTS + k) * YL + iy) * XL + ix);
            out[e] = val;
        }
    } else if (tid < NP * NPTS + NP) {
        int p = tid - NP * NPTS;
        int b = coors[3 * p], ix = coors[3 * p + 1], iy = coors[3 * p + 2];
        const float4* src = reinterpret_cast<const float4*>(pillars + (long long)p * 96);
        float s[3] = {0.f, 0.f, 0.f};
#pragma unroll
        for (int i = 0; i < 24; ++i) {
            float4 q = src[i];
            s[(4 * i + 0) % 3] += q.x;
            s[(4 * i + 1) % 3] += q.y;
            s[(4 * i + 2) % 3] += q.z;
            s[(4 * i + 3) % 3] += q.w;
        }
        float inv = 1.0f / (float)npoints[p];
#pragma unroll
        for (int c = 0; c < 3; ++c) {
            long long e = OFF_CTR + (((long long)(b * 3 + c) * YL + iy) * XL + ix);
            out[e] = s[c] * inv;
        }
    }
}

__global__ __launch_bounds__(256) void smallcvt_kernel(
    const int* __restrict__ coors, const int* __restrict__ npoints,
    float* __restrict__ out)
{
    constexpr int NC = (int)(SZ_C / 4);
    constexpr int NN = (int)(SZ_N / 4);
    int u = blockIdx.x * 256 + threadIdx.x;
    if (u >= NC + NN) return;
    int4 a; long long dst;
    if (u < NC) { a = reinterpret_cast<const int4*>(coors)[u]; dst = SZ_P / 4 + u; }
    else { a = reinterpret_cast<const int4*>(npoints)[u - NC]; dst = SZ_P / 4 + NC + (u - NC); }
    reinterpret_cast<float4*>(out)[dst] =
        float4{(float)a.x, (float)a.y, (float)a.z, (float)a.w};
}

extern "C" void kernel_launch(void* const* d_in, const int* in_sizes, int n_in,
                              void* d_out, int out_size, void* d_ws, size_t ws_size,
                              hipStream_t stream) {
    const float* pillars = (const float*)d_in[0];
    const int*   coors   = (const int*)d_in[1];
    const int*   npoints = (const int*)d_in[2];
    float*       out     = (float*)d_out;

    const size_t mapBytes = (size_t)BS * YL * XL * sizeof(int);   // 3,428,352

    if (ws_size >= mapBytes) {
        int* map = (int*)d_ws;
        (void)hipMemsetAsync(map, 0xFF, mapBytes, stream);        // all cells -> -1
        build_map<<<(NP + 255) / 256, 256, 0, stream>>>(coors, map);
        mega_kernel<<<NB_MEGA, 256, 0, stream>>>(pillars, coors, npoints, map, out);
    } else {
        // fallback: zero big regions, copy/convert small regions, scatter
        (void)hipMemcpyAsync(out, pillars, (size_t)SZ_P * sizeof(float),
                             hipMemcpyDeviceToDevice, stream);
        (void)hipMemsetAsync(out + OFF_ALL, 0, (size_t)(SZ_ALL + SZ_CTR) * sizeof(float), stream);
        smallcvt_kernel<<<(int)((SZ_C / 4 + SZ_N / 4 + 255) / 256), 256, 0, stream>>>(
            coors, npoints, out);
        int nthr = NP * NPTS + NP;
        scatter_kernel<<<(nthr + 255) / 256, 256, 0, stream>>>(pillars, coors, npoints, out);
    }
}